// Round 1
// baseline (965.981 us; speedup 1.0000x reference)
//
#include <hip/hip_runtime.h>
#include <math.h>

#define SLOPE 0.01f

__device__ __forceinline__ float lrelu(float v) { return v >= 0.f ? v : SLOPE * v; }

// ---------------------------------------------------------------------------
// Tiny kernel: GRU step (h0=0) for both layers, regenerate GCN weights,
// fold Wout/bout into a single 16-vector + scalar.
// ---------------------------------------------------------------------------
__global__ void prep_k(const float* __restrict__ m1, const float* __restrict__ Wih1,
                       const float* __restrict__ bih1, const float* __restrict__ bhh1,
                       const float* __restrict__ m2, const float* __restrict__ Wih2,
                       const float* __restrict__ bih2, const float* __restrict__ bhh2,
                       const float* __restrict__ wtW1, const float* __restrict__ wtb1,
                       const float* __restrict__ wtW2, const float* __restrict__ wtb2,
                       const float* __restrict__ Wout, const float* __restrict__ bout,
                       float* __restrict__ Wn1, float* __restrict__ Wn2,
                       float* __restrict__ wsum, float* __restrict__ bsum) {
    __shared__ float nm[32];   // new_mem1 [0..15], new_mem2 [16..31]
    int t = threadIdx.x;
    if (t < 32) {
        int L = t >> 4, j = t & 15;
        const float* m   = L ? m2   : m1;
        const float* Wih = L ? Wih2 : Wih1;
        const float* bih = L ? bih2 : bih1;
        const float* bhh = L ? bhh2 : bhh1;
        // gi = Wih @ mem + bih ; gh = bhh (hidden state is zero)
        float gr = bih[j], gz = bih[16 + j], gn = bih[32 + j];
        for (int k = 0; k < 16; ++k) {
            float mk = m[k];
            gr += Wih[j * 16 + k] * mk;
            gz += Wih[(16 + j) * 16 + k] * mk;
            gn += Wih[(32 + j) * 16 + k] * mk;
        }
        float r = 1.f / (1.f + expf(-(gr + bhh[j])));
        float z = 1.f / (1.f + expf(-(gz + bhh[16 + j])));
        float n = tanhf(gn + r * bhh[32 + j]);
        nm[t] = (1.f - z) * n;          // + z*h, h==0
    }
    __syncthreads();
    // Wnew = wtW @ new_mem + wtb   (256 outputs each layer; t covers both)
    float s1 = wtb1[t], s2 = wtb2[t];
    for (int k = 0; k < 16; ++k) {
        s1 += wtW1[t * 16 + k] * nm[k];
        s2 += wtW2[t * 16 + k] * nm[16 + k];
    }
    Wn1[t] = s1;
    Wn2[t] = s2;
    if (t < 16) wsum[t] = Wout[t] + Wout[16 + t];
    if (t == 0) bsum[0] = bout[0] + bout[1];
}

// ---------------------------------------------------------------------------
// init: agg <- bias broadcast ; deg <- 1 (self-loop)
// ---------------------------------------------------------------------------
__global__ void init1_k(float* __restrict__ agg, const float* __restrict__ b,
                        float* __restrict__ deg, int N) {
    int t = blockIdx.x * 256 + threadIdx.x;
    if (t < N * 16) agg[t] = b[t & 15];
    if (t < N) deg[t] = 1.f;
}

__global__ void init2_k(float* __restrict__ agg, const float* __restrict__ b, int N) {
    int t = blockIdx.x * 256 + threadIdx.x;
    if (t < N * 16) agg[t] = b[t & 15];
}

__global__ void deg_k(float* __restrict__ deg, const int* __restrict__ col, int E) {
    int e = blockIdx.x * 256 + threadIdx.x;
    if (e < E) atomicAdd(deg + col[e], 1.f);
}

__global__ void dis_k(float* __restrict__ deg, int N) {
    int i = blockIdx.x * 256 + threadIdx.x;
    if (i < N) deg[i] = 1.f / sqrtf(deg[i]);   // deg >= 1 always (self-loop)
}

// ---------------------------------------------------------------------------
// Fused MLP: xl1 = (leaky(leaky(x@W1^T + b1)@W2^T + b2)) @ Wnew1^T
// Thread-per-node; x row lives in 128 VGPRs; W1/W2/Wn1 are lane-uniform ->
// scalar (s_load) broadcast.
// ---------------------------------------------------------------------------
__global__ __launch_bounds__(256, 1) void mlp_k(
        const float* __restrict__ x, const float* __restrict__ W1,
        const float* __restrict__ b1, const float* __restrict__ W2,
        const float* __restrict__ b2, const float* __restrict__ Wn1,
        float* __restrict__ xl, int N) {
    int i = blockIdx.x * 256 + threadIdx.x;
    if (i >= N) return;

    float4 xr[32];
    const float4* xrow = (const float4*)(x + (size_t)i * 128);
#pragma unroll
    for (int k = 0; k < 32; ++k) xr[k] = xrow[k];

    float acc2[16];
#pragma unroll
    for (int j = 0; j < 16; ++j) acc2[j] = b2[j];

    for (int hu = 0; hu < 256; ++hu) {
        const float4* w = (const float4*)(W1 + hu * 128);
        float a0 = 0.f, a1 = 0.f, a2 = 0.f, a3 = 0.f;
#pragma unroll
        for (int k = 0; k < 32; ++k) {
            float4 wv = w[k];
            float4 xv = xr[k];
            a0 = fmaf(xv.x, wv.x, a0);
            a1 = fmaf(xv.y, wv.y, a1);
            a2 = fmaf(xv.z, wv.z, a2);
            a3 = fmaf(xv.w, wv.w, a3);
        }
        float h1 = lrelu(((a0 + a1) + (a2 + a3)) + b1[hu]);
#pragma unroll
        for (int j = 0; j < 16; ++j) acc2[j] = fmaf(W2[j * 256 + hu], h1, acc2[j]);
    }

    float h2[16];
#pragma unroll
    for (int j = 0; j < 16; ++j) h2[j] = lrelu(acc2[j]);

    float o[16];
#pragma unroll
    for (int c = 0; c < 16; ++c) {
        float s = 0.f;
#pragma unroll
        for (int j = 0; j < 16; ++j) s = fmaf(Wn1[c * 16 + j], h2[j], s);
        o[c] = s;
    }
    float4* xo = (float4*)(xl + (size_t)i * 16);
#pragma unroll
    for (int q = 0; q < 4; ++q)
        xo[q] = make_float4(o[4 * q], o[4 * q + 1], o[4 * q + 2], o[4 * q + 3]);
}

// ---------------------------------------------------------------------------
// Scatter: agg[col] += xl[row] * dis[row]*dis[col]  over E edges + N self-loops
// one thread per (edge, channel)
// ---------------------------------------------------------------------------
__global__ void scat_k(const int* __restrict__ row, const int* __restrict__ col,
                       const float* __restrict__ xl, const float* __restrict__ dis,
                       float* __restrict__ agg, int E, int N) {
    int t = blockIdx.x * 256 + threadIdx.x;
    int e = t >> 4;
    if (e >= E + N) return;
    int c = t & 15;
    int r, d;
    if (e < E) { r = row[e]; d = col[e]; }
    else       { r = e - E;  d = r; }
    float nrm = dis[r] * dis[d];
    atomicAdd(agg + (size_t)d * 16 + c, xl[(size_t)r * 16 + c] * nrm);
}

// ---------------------------------------------------------------------------
// xl2 = leaky(agg1) @ Wnew2^T   (thread-per-node, Wnew2 via LDS broadcast)
// ---------------------------------------------------------------------------
__global__ void xl2_k(const float* __restrict__ agg, const float* __restrict__ Wn,
                      float* __restrict__ xl, int N) {
    __shared__ float w[256];
    w[threadIdx.x] = Wn[threadIdx.x];
    __syncthreads();
    int i = blockIdx.x * 256 + threadIdx.x;
    if (i >= N) return;
    float h[16];
    const float4* a4 = (const float4*)(agg + (size_t)i * 16);
#pragma unroll
    for (int q = 0; q < 4; ++q) {
        float4 v = a4[q];
        h[4 * q]     = lrelu(v.x);
        h[4 * q + 1] = lrelu(v.y);
        h[4 * q + 2] = lrelu(v.z);
        h[4 * q + 3] = lrelu(v.w);
    }
    float o[16];
#pragma unroll
    for (int c = 0; c < 16; ++c) {
        float s = 0.f;
#pragma unroll
        for (int j = 0; j < 16; ++j) s = fmaf(w[c * 16 + j], h[j], s);
        o[c] = s;
    }
    float4* xo = (float4*)(xl + (size_t)i * 16);
#pragma unroll
    for (int q = 0; q < 4; ++q)
        xo[q] = make_float4(o[4 * q], o[4 * q + 1], o[4 * q + 2], o[4 * q + 3]);
}

// ---------------------------------------------------------------------------
// out[i] = sum_c leaky(agg2[i][c]) * (Wout[0][c]+Wout[1][c]) + (bout0+bout1)
// ---------------------------------------------------------------------------
__global__ void final_k(const float* __restrict__ agg, const float* __restrict__ wsum,
                        const float* __restrict__ bsum, float* __restrict__ out, int N) {
    int i = blockIdx.x * 256 + threadIdx.x;
    if (i >= N) return;
    const float4* a4 = (const float4*)(agg + (size_t)i * 16);
    float s = bsum[0];
#pragma unroll
    for (int q = 0; q < 4; ++q) {
        float4 v = a4[q];
        s = fmaf(wsum[4 * q],     lrelu(v.x), s);
        s = fmaf(wsum[4 * q + 1], lrelu(v.y), s);
        s = fmaf(wsum[4 * q + 2], lrelu(v.z), s);
        s = fmaf(wsum[4 * q + 3], lrelu(v.w), s);
    }
    out[i] = s;
}

// ---------------------------------------------------------------------------
extern "C" void kernel_launch(void* const* d_in, const int* in_sizes, int n_in,
                              void* d_out, int out_size, void* d_ws, size_t ws_size,
                              hipStream_t stream) {
    const float* x      = (const float*)d_in[0];
    const int*   edge   = (const int*)d_in[1];
    const float* W1     = (const float*)d_in[2];
    const float* b1     = (const float*)d_in[3];
    const float* W2     = (const float*)d_in[4];
    const float* b2     = (const float*)d_in[5];
    const float* mem1   = (const float*)d_in[6];
    const float* g1_Wih = (const float*)d_in[7];
    // d_in[8] = g1_Whh: multiplied by h0==0, unused
    const float* g1_bih = (const float*)d_in[9];
    const float* g1_bhh = (const float*)d_in[10];
    const float* wt1_W  = (const float*)d_in[11];
    const float* wt1_b  = (const float*)d_in[12];
    const float* gcn1_b = (const float*)d_in[13];
    const float* mem2   = (const float*)d_in[14];
    const float* g2_Wih = (const float*)d_in[15];
    const float* g2_bih = (const float*)d_in[17];
    const float* g2_bhh = (const float*)d_in[18];
    const float* wt2_W  = (const float*)d_in[19];
    const float* wt2_b  = (const float*)d_in[20];
    const float* gcn2_b = (const float*)d_in[21];
    const float* Wout   = (const float*)d_in[22];
    const float* bout   = (const float*)d_in[23];
    float* out = (float*)d_out;

    const int N = in_sizes[0] / 128;
    const int E = in_sizes[1] / 2;
    const int* row = edge;
    const int* col = edge + E;

    float* ws   = (float*)d_ws;
    float* bufA = ws;                        // [N*16] xl buffer
    float* bufB = bufA + (size_t)N * 16;     // [N*16] agg buffer
    float* deg  = bufB + (size_t)N * 16;     // [N]    degree -> dis (in place)
    float* sm   = deg + N;                   // smalls
    float* Wn1  = sm;
    float* Wn2  = sm + 256;
    float* wsum = sm + 512;
    float* bsum = sm + 528;

    const int gN   = (N + 255) / 256;
    const int gN16 = (N * 16 + 255) / 256;
    const int gE   = (E + 255) / 256;
    const int gS   = ((E + N) * 16 + 255) / 256;

    prep_k<<<1, 256, 0, stream>>>(mem1, g1_Wih, g1_bih, g1_bhh,
                                  mem2, g2_Wih, g2_bih, g2_bhh,
                                  wt1_W, wt1_b, wt2_W, wt2_b,
                                  Wout, bout, Wn1, Wn2, wsum, bsum);
    init1_k<<<gN16, 256, 0, stream>>>(bufB, gcn1_b, deg, N);
    deg_k<<<gE, 256, 0, stream>>>(deg, col, E);
    dis_k<<<gN, 256, 0, stream>>>(deg, N);
    mlp_k<<<gN, 256, 0, stream>>>(x, W1, b1, W2, b2, Wn1, bufA, N);
    scat_k<<<gS, 256, 0, stream>>>(row, col, bufA, deg, bufB, E, N);
    xl2_k<<<gN, 256, 0, stream>>>(bufB, Wn2, bufA, N);
    init2_k<<<gN16, 256, 0, stream>>>(bufB, gcn2_b, N);
    scat_k<<<gS, 256, 0, stream>>>(row, col, bufA, deg, bufB, E, N);
    final_k<<<gN, 256, 0, stream>>>(bufB, wsum, bsum, out, N);
}